// Round 19
// baseline (181.600 us; speedup 1.0000x reference)
//
#include <hip/hip_runtime.h>
#include <hip/hip_bf16.h>

#define BB 64
#define LL 800
#define DD 100
#define NFC 50
#define MPAD 832
#define XROWS 896
#define DPAD 128

typedef __attribute__((ext_vector_type(8))) short short8;
typedef __attribute__((ext_vector_type(4))) float f32x4;
#define MFMA16(a, b, c) __builtin_amdgcn_mfma_f32_16x16x32_bf16(a, b, c, 0, 0, 0)

struct ConvP {
  const float* w[8];
  const float* bias[8];
};

__device__ __forceinline__ ushort f2bf(float f) {
  unsigned u = __float_as_uint(f);
  u += 0x7fff + ((u >> 16) & 1);
  return (ushort)(u >> 16);
}
__device__ __forceinline__ float bf2f(short s) {
  return __uint_as_float(((unsigned)(ushort)s) << 16);
}
__device__ __forceinline__ unsigned cvtpk(float lo, float hi) {
  unsigned d;
  asm("v_cvt_pk_bf16_f32 %0, %1, %2" : "=v"(d) : "v"(lo), "v"(hi));
  return d;
}
__device__ __forceinline__ void swap3216(unsigned& a, unsigned& b) {
  asm("v_permlane32_swap_b32 %0, %1\n\t"
      "v_permlane16_swap_b32 %0, %1"
      : "+v"(a), "+v"(b));
}

// ---- prep: blocks 0..895 gather+transpose (14 tiles/b; tile 13 zeros rows
// 832-895); 896..2175 weight pack; 2176..2275 feat zero-init ----
__global__ __launch_bounds__(256) void k_prep(const int* __restrict__ x,
                                              const float* __restrict__ emb,
                                              const int* __restrict__ mask,
                                              short* __restrict__ xeb,
                                              short* __restrict__ xeT,
                                              ConvP P, short* __restrict__ wb,
                                              int* __restrict__ feat) {
  int bid = blockIdx.x;
  int t = threadIdx.x;
  if (bid >= 896) {
    if (bid >= 2176) {  // feat init
      int idx = (bid - 2176) * 256 + t;
      if (idx < BB * 2 * 4 * NFC) feat[idx] = 0;
      return;
    }
    // weight pack: wb[br][sz][nf(64)][i(5)][d(128)] zero-padded
    int idx = (bid - 896) * 256 + t;
    int d = idx & 127;
    int r = idx >> 7;
    int i = r % 5; r /= 5;
    int nf = r & 63; r >>= 6;
    int sz = r & 3;
    int br = r >> 2;
    int s = (sz < 3) ? sz + 1 : 5;
    float v = 0.f;
    if (nf < NFC && i < s && d < DD) v = P.w[br * 4 + sz][(nf * s + i) * DD + d];
    wb[idx] = (short)f2bf(v);
    return;
  }
  __shared__ float tile[64][129];
  __shared__ int toks[64];
  __shared__ float msk[64];
  int xcd = bid & 7, slot = bid >> 3;
  int b = xcd + 8 * (slot / 14);
  int mt = slot % 14;
  int m0 = mt * 64;
  if (t < 64) {
    int gm = m0 + t;
    toks[t] = (gm < LL) ? x[b * LL + gm] : 1;
    msk[t] = (gm < LL) ? (float)mask[b * LL + gm] : 0.f;
  }
  __syncthreads();
  for (int i = t; i < 64 * 128; i += 256) {
    int m = i >> 7, d = i & 127;
    int gm = m0 + m;
    float v = 0.f;
    if (gm < LL && d < DD) v = emb[(size_t)toks[m] * DD + d];
    tile[m][d] = v;
    xeb[((size_t)b * XROWS + gm) * DPAD + d] = (short)f2bf(v);
  }
  __syncthreads();
  if (m0 < MPAD) {  // xeT has only 832 m-columns
    for (int i = t; i < 64 * 128; i += 256) {
      int m = i & 63, d = i >> 6;
      float mk = msk[m];
      float v;
      if (d < DD) v = tile[m][d] * mk;
      else if (d == DD) v = mk;
      else if (d == DD + 1) v = (m0 + m < LL) ? 1.f : 0.f;
      else v = 0.f;
      xeT[((size_t)b * DPAD + d) * MPAD + m0 + m] = (short)f2bf(v);
    }
  }
}

// ---- MFMA attention v8: R16 structure exactly (256 thr, 4 waves x 32 l-cols,
// 128-l tiles, grid 448, single 1-deep R[4] staging, VGPR ~80) with the ONE
// validated delta: conflict-free strides ASTR=140 / BSTR=36 (R18: 4.3x fewer
// bank conflicts; no extra registers -> no spill at (256,3)). ----
#define ASTR 140
#define BSTR 36
#define BOFF (32 * ASTR)
#define SBSZ (BOFF + 112 * BSTR)
__global__ __launch_bounds__(256, 3) void k_attn(const short* __restrict__ xeb,
                                                 const short* __restrict__ xeT,
                                                 const int* __restrict__ mask,
                                                 short* __restrict__ xhb) {
  __shared__ __align__(16) short SB[2][SBSZ];
  int bid = blockIdx.x;
  int xcd = bid & 7, slot = bid >> 3;  // batch -> XCD: panels stay L2-local
  int b = xcd + 8 * (slot / 7);
  int lt = slot % 7;
  int l0 = lt * 128;
  int t = threadIdx.x, w = t >> 6, lane = t & 63, g = lane >> 4, c = lane & 15;
  int lcolA = l0 + 32 * w + c;
  int lcolB = lcolA + 16;

  const short* xebB = xeb + (size_t)b * XROWS * DPAD;
  const short* xTb = xeT + (size_t)b * DPAD * MPAD;

  const short* ssrc[4];
  int sdst[4], sstep[4];
  bool sval[4];
#pragma unroll
  for (int p = 0; p < 4; ++p) {
    int q = p * 256 + t;
    if (q < 512) {  // As: row r of 32-m tile, 16B piece j
      int r = q >> 4, j = q & 15;
      ssrc[p] = xebB + r * DPAD + j * 8;
      sstep[p] = 32 * DPAD;
      sdst[p] = r * ASTR + j * 8;
      sval[p] = true;
    } else {  // Bs: row r (d-dim), 16B piece j of the 32-m slice
      int u = q - 512;
      int r = u >> 2, j = u & 3;
      ssrc[p] = xTb + r * MPAD + j * 8;
      sstep[p] = 32;
      sdst[p] = BOFF + r * BSTR + j * 8;
      sval[p] = (u < 448);
    }
  }

  short8 xlfA[4], xlfB[4];
  {
    const short* ra = xebB + (size_t)lcolA * DPAD + 8 * g;
    const short* rb = xebB + (size_t)lcolB * DPAD + 8 * g;
#pragma unroll
    for (int ks = 0; ks < 4; ++ks) {
      xlfA[ks] = *reinterpret_cast<const short8*>(ra + 32 * ks);
      xlfB[ks] = *reinterpret_cast<const short8*>(rb + 32 * ks);
    }
  }

  f32x4 pvA[7], pvB[7];
#pragma unroll
  for (int dt = 0; dt < 7; ++dt) {
    pvA[dt] = (f32x4){0.f, 0.f, 0.f, 0.f};
    pvB[dt] = (f32x4){0.f, 0.f, 0.f, 0.f};
  }

  uint4 R[4];
#pragma unroll
  for (int p = 0; p < 4; ++p) {
    if (sval[p]) R[p] = *reinterpret_cast<const uint4*>(ssrc[p]);
    ssrc[p] += sstep[p];
  }

  int cur = 0;
  for (int mc = 0; mc < 26; ++mc) {
    int m0 = mc * 32;
#pragma unroll
    for (int p = 0; p < 4; ++p)
      if (sval[p]) *reinterpret_cast<short8*>(&SB[cur][sdst[p]]) =
          *reinterpret_cast<const short8*>(&R[p]);
    if (mc < 25) {
#pragma unroll
      for (int p = 0; p < 4; ++p) {
        if (sval[p]) R[p] = *reinterpret_cast<const uint4*>(ssrc[p]);
        ssrc[p] += sstep[p];
      }
    }
    asm volatile("s_waitcnt lgkmcnt(0)" ::: "memory");
    __builtin_amdgcn_s_barrier();
    __builtin_amdgcn_sched_barrier(0);

    const short* asb = SB[cur];
    const short* bsb = SB[cur] + BOFF;

    f32x4 sA0 = {0.f, 0.f, 0.f, 0.f}, sA1 = sA0, sB0 = sA0, sB1 = sA0;
    __builtin_amdgcn_s_setprio(1);
#pragma unroll
    for (int ks = 0; ks < 4; ++ks) {
      short8 af0 = *reinterpret_cast<const short8*>(asb + c * ASTR + 8 * g + 32 * ks);
      short8 af1 = *reinterpret_cast<const short8*>(asb + (c + 16) * ASTR + 8 * g + 32 * ks);
      sA0 = MFMA16(af0, xlfA[ks], sA0);
      sB0 = MFMA16(af0, xlfB[ks], sB0);
      sA1 = MFMA16(af1, xlfA[ks], sA1);
      sB1 = MFMA16(af1, xlfB[ks], sB1);
    }
    __builtin_amdgcn_s_setprio(0);

    float eA00 = __expf(sA0[0]), eA01 = __expf(sA0[1]), eA02 = __expf(sA0[2]), eA03 = __expf(sA0[3]);
    float eA10 = __expf(sA1[0]), eA11 = __expf(sA1[1]), eA12 = __expf(sA1[2]), eA13 = __expf(sA1[3]);
    float eB00 = __expf(sB0[0]), eB01 = __expf(sB0[1]), eB02 = __expf(sB0[2]), eB03 = __expf(sB0[3]);
    float eB10 = __expf(sB1[0]), eB11 = __expf(sB1[1]), eB12 = __expf(sB1[2]), eB13 = __expf(sB1[3]);
    if ((mc >> 2) == lt) {
      int md = m0 + 4 * g;
      eA00 = (md + 0 == lcolA) ? 0.f : eA00;
      eA01 = (md + 1 == lcolA) ? 0.f : eA01;
      eA02 = (md + 2 == lcolA) ? 0.f : eA02;
      eA03 = (md + 3 == lcolA) ? 0.f : eA03;
      eA10 = (md + 16 == lcolA) ? 0.f : eA10;
      eA11 = (md + 17 == lcolA) ? 0.f : eA11;
      eA12 = (md + 18 == lcolA) ? 0.f : eA12;
      eA13 = (md + 19 == lcolA) ? 0.f : eA13;
      eB00 = (md + 0 == lcolB) ? 0.f : eB00;
      eB01 = (md + 1 == lcolB) ? 0.f : eB01;
      eB02 = (md + 2 == lcolB) ? 0.f : eB02;
      eB03 = (md + 3 == lcolB) ? 0.f : eB03;
      eB10 = (md + 16 == lcolB) ? 0.f : eB10;
      eB11 = (md + 17 == lcolB) ? 0.f : eB11;
      eB12 = (md + 18 == lcolB) ? 0.f : eB12;
      eB13 = (md + 19 == lcolB) ? 0.f : eB13;
    }
    unsigned a0 = cvtpk(eA00, eA01), a1 = cvtpk(eA02, eA03);
    unsigned a2 = cvtpk(eA10, eA11), a3 = cvtpk(eA12, eA13);
    swap3216(a0, a2);
    swap3216(a1, a3);
    union { unsigned u[4]; short8 v; } paA;
    paA.u[0] = a0; paA.u[1] = a1; paA.u[2] = a2; paA.u[3] = a3;
    unsigned b0 = cvtpk(eB00, eB01), b1 = cvtpk(eB02, eB03);
    unsigned b2 = cvtpk(eB10, eB11), b3 = cvtpk(eB12, eB13);
    swap3216(b0, b2);
    swap3216(b1, b3);
    union { unsigned u[4]; short8 v; } paB;
    paB.u[0] = b0; paB.u[1] = b1; paB.u[2] = b2; paB.u[3] = b3;

    __builtin_amdgcn_s_setprio(1);
#pragma unroll
    for (int dt = 0; dt < 7; ++dt) {
      short8 bf = *reinterpret_cast<const short8*>(bsb + (c + 16 * dt) * BSTR + 8 * g);
      pvA[dt] = MFMA16(paA.v, bf, pvA[dt]);
      pvB[dt] = MFMA16(paB.v, bf, pvB[dt]);
    }
    __builtin_amdgcn_s_setprio(0);
    cur ^= 1;
  }

  // epilogue: S2 = out col 100 (lane c=4), Z = out col 101 (lane c=5)
#pragma unroll
  for (int half = 0; half < 2; ++half) {
#pragma unroll
    for (int r = 0; r < 4; ++r) {
      int lrow = l0 + 32 * w + 16 * half + 4 * g + r;
      f32x4* pv = half ? pvB : pvA;
      float S2r = __shfl(pv[6][r], 16 * g + 4);
      float Zr = __shfl(pv[6][r], 16 * g + 5) + 1.0f;  // +1: diag exp(0)
      short* xhr = xhb + ((size_t)b * XROWS + lrow) * DPAD;
      if (lrow < LL) {
        float mlr = (float)mask[b * LL + lrow];
        float inv = mlr / (mlr * S2r + Zr * 1e-13f);
        const short* xer = xebB + (size_t)lrow * DPAD;
#pragma unroll
        for (int dt = 0; dt < 7; ++dt) {
          int d = 16 * dt + c;
          xhr[d] = (d < DD) ? (short)f2bf(pv[dt][r] * inv + bf2f(xer[d])) : (short)0;
        }
        xhr[112 + c] = 0;
      } else {
#pragma unroll
        for (int dt = 0; dt < 8; ++dt) xhr[16 * dt + c] = 0;
      }
    }
  }
}

// ---- conv v5 (R16, unchanged): 2 l-tiles per block, weight frag feeds 8 MFMAs ----
__global__ __launch_bounds__(256, 2) void k_conv(const short* __restrict__ xeb,
                                                 const short* __restrict__ xhb,
                                                 const short* __restrict__ wb,
                                                 ConvP P, int* __restrict__ feat) {
  __shared__ __align__(16) short SB[2][68 * 128];
  int bid = blockIdx.x;
  int xcd = bid & 7, slot = bid >> 3;  // batch -> XCD map (L2-local x panels)
  int b = xcd + 8 * (slot / 14);
  int rem = slot % 14;
  int br = rem >= 7;
  int q = rem % 7;
  int l0 = q * 128;
  const short* src = (br ? xhb : xeb) + (size_t)b * XROWS * DPAD;
  int t = threadIdx.x;
  int w = t >> 6, lane = t & 63, g = lane >> 4, c = lane & 15;
  int nf = w * 16 + c;
  const short* wpb = wb + (size_t)(br * 4) * 64 * 640 + (size_t)nf * 640 + 8 * g;

  float bias0 = (nf < NFC) ? P.bias[br * 4 + 0][nf] : 0.f;
  float bias1 = (nf < NFC) ? P.bias[br * 4 + 1][nf] : 0.f;
  float bias2 = (nf < NFC) ? P.bias[br * 4 + 2][nf] : 0.f;
  float bias3 = (nf < NFC) ? P.bias[br * 4 + 3][nf] : 0.f;

  // stage 2 tiles of 68x128 bf16, XOR-swizzled 16B chunks (chunk ^= row&7)
#pragma unroll
  for (int tt = 0; tt < 2; ++tt) {
    for (int i = t; i < 68 * 16; i += 256) {
      int row = i >> 4, c16 = i & 15;
      int gr = l0 + tt * 64 + row;
      if (gr > XROWS - 1) gr = XROWS - 1;  // rows >=800 are zero
      short8 v = *reinterpret_cast<const short8*>(src + (size_t)gr * DPAD + c16 * 8);
      *reinterpret_cast<short8*>(&SB[tt][row * 128 + ((c16 ^ (row & 7)) << 3)]) = v;
    }
  }
  __syncthreads();

  f32x4 acc[8][4];
#pragma unroll
  for (int ls = 0; ls < 8; ++ls)
#pragma unroll
    for (int sz = 0; sz < 4; ++sz) acc[ls][sz] = (f32x4){0.f, 0.f, 0.f, 0.f};

#pragma unroll
  for (int i2 = 0; i2 < 5; ++i2) {
#pragma unroll
    for (int ks = 0; ks < 4; ++ks) {
      short8 af[8];
#pragma unroll
      for (int tt = 0; tt < 2; ++tt)
#pragma unroll
        for (int ls = 0; ls < 4; ++ls) {
          int row = ls * 16 + c + i2;
          af[tt * 4 + ls] = *reinterpret_cast<const short8*>(
              &SB[tt][row * 128 + (((4 * ks + g) ^ (row & 7)) << 3)]);
        }
      const short* wpk = wpb + i2 * 128 + ks * 32;
      if (i2 < 1) {
        short8 w0 = *reinterpret_cast<const short8*>(wpk + (size_t)0 * 40960);
#pragma unroll
        for (int u = 0; u < 8; ++u) acc[u][0] = MFMA16(af[u], w0, acc[u][0]);
      }
      if (i2 < 2) {
        short8 w1 = *reinterpret_cast<const short8*>(wpk + (size_t)1 * 40960);
#pragma unroll
        for (int u = 0; u < 8; ++u) acc[u][1] = MFMA16(af[u], w1, acc[u][1]);
      }
      if (i2 < 3) {
        short8 w2 = *reinterpret_cast<const short8*>(wpk + (size_t)2 * 40960);
#pragma unroll
        for (int u = 0; u < 8; ++u) acc[u][2] = MFMA16(af[u], w2, acc[u][2]);
      }
      {
        short8 w3 = *reinterpret_cast<const short8*>(wpk + (size_t)3 * 40960);
#pragma unroll
        for (int u = 0; u < 8; ++u) acc[u][3] = MFMA16(af[u], w3, acc[u][3]);
      }
    }
  }

  float mx0 = 0.f, mx1 = 0.f, mx2 = 0.f, mx3 = 0.f;
#pragma unroll
  for (int u = 0; u < 8; ++u) {
    int lbase = l0 + (u >> 2) * 64 + (u & 3) * 16 + 4 * g;
#pragma unroll
    for (int r = 0; r < 4; ++r) {
      int l = lbase + r;
      float v0 = acc[u][0][r] + bias0; v0 = v0 > 0.f ? v0 : 0.f;
      float v1 = acc[u][1][r] + bias1; v1 = v1 > 0.f ? v1 : 0.f;
      float v2 = acc[u][2][r] + bias2; v2 = v2 > 0.f ? v2 : 0.f;
      float v3 = acc[u][3][r] + bias3; v3 = v3 > 0.f ? v3 : 0.f;
      if (l < LL - 0) mx0 = fmaxf(mx0, v0);
      if (l < LL - 1) mx1 = fmaxf(mx1, v1);
      if (l < LL - 2) mx2 = fmaxf(mx2, v2);
      if (l < LL - 4) mx3 = fmaxf(mx3, v3);
    }
  }

  mx0 = fmaxf(mx0, __shfl_xor(mx0, 16));
  mx0 = fmaxf(mx0, __shfl_xor(mx0, 32));
  mx1 = fmaxf(mx1, __shfl_xor(mx1, 16));
  mx1 = fmaxf(mx1, __shfl_xor(mx1, 32));
  mx2 = fmaxf(mx2, __shfl_xor(mx2, 16));
  mx2 = fmaxf(mx2, __shfl_xor(mx2, 32));
  mx3 = fmaxf(mx3, __shfl_xor(mx3, 16));
  mx3 = fmaxf(mx3, __shfl_xor(mx3, 32));
  if (g == 0 && nf < NFC) {
    int base = (b * 2 + br) * 4;
    atomicMax(&feat[(base + 0) * NFC + nf], __float_as_int(mx0));
    atomicMax(&feat[(base + 1) * NFC + nf], __float_as_int(mx1));
    atomicMax(&feat[(base + 2) * NFC + nf], __float_as_int(mx2));
    atomicMax(&feat[(base + 3) * NFC + nf], __float_as_int(mx3));
  }
}

// ---------------- FC + branch sum ----------------
__global__ __launch_bounds__(256) void k_fc(const float* __restrict__ feat,
                                            const float* __restrict__ fw1,
                                            const float* __restrict__ fb1,
                                            const float* __restrict__ fw2,
                                            const float* __restrict__ fb2,
                                            float* __restrict__ out) {
  int id = blockIdx.x * 256 + threadIdx.x;
  if (id >= BB * NFC) return;
  int b = id / NFC, k = id - b * NFC;
  float a = fb1[k] + fb2[k];
  const float* f1 = feat + (size_t)(b * 2 + 0) * (4 * NFC);
  const float* f2 = feat + (size_t)(b * 2 + 1) * (4 * NFC);
  const float* w1 = fw1 + k * (4 * NFC);
  const float* w2 = fw2 + k * (4 * NFC);
  for (int j = 0; j < 4 * NFC; ++j) a += f1[j] * w1[j] + f2[j] * w2[j];
  out[id] = a;
}

extern "C" void kernel_launch(void* const* d_in, const int* in_sizes, int n_in,
                              void* d_out, int out_size, void* d_ws, size_t ws_size,
                              hipStream_t stream) {
  const int* x = (const int*)d_in[0];
  const int* mask = (const int*)d_in[2];
  const float* emb = (const float*)d_in[3];
  ConvP P;
  for (int br = 0; br < 2; ++br)
    for (int j = 0; j < 4; ++j) {
      P.w[br * 4 + j] = (const float*)d_in[4 + br * 10 + j * 2];
      P.bias[br * 4 + j] = (const float*)d_in[4 + br * 10 + j * 2 + 1];
    }
  const float* fw1 = (const float*)d_in[12];
  const float* fb1 = (const float*)d_in[13];
  const float* fw2 = (const float*)d_in[22];
  const float* fb2 = (const float*)d_in[23];

  char* base = (char*)d_ws;
  short* xeb = (short*)base;                    // 64*896*128*2 = 14,680,064 B
  short* xeT = (short*)(base + 14680064);       // 64*128*832*2 = 13,631,488 B
  short* xhb = (short*)(base + 28311552);       // 14,680,064 B
  short* wb = (short*)(base + 42991616);        //    655,360 B
  int* feat = (int*)(base + 43646976);          //    102,400 B
  float* out = (float*)d_out;

  k_prep<<<2276, 256, 0, stream>>>(x, emb, mask, xeb, xeT, P, wb, feat);
  k_attn<<<BB * 7, 256, 0, stream>>>(xeb, xeT, mask, xhb);
  k_conv<<<BB * 2 * 7, 256, 0, stream>>>(xeb, xhb, wb, P, feat);
  k_fc<<<(BB * NFC + 255) / 256, 256, 0, stream>>>((const float*)feat, fw1, fb1,
                                                   fw2, fb2, out);
}

// Round 20
// 113.726 us; speedup vs baseline: 1.5968x; 1.5968x over previous
//
#include <hip/hip_runtime.h>
#include <hip/hip_bf16.h>

#define BB 64
#define LL 800
#define DD 100
#define NFC 50
#define MPAD 832
#define XROWS 896
#define DPAD 128

typedef __attribute__((ext_vector_type(8))) short short8;
typedef __attribute__((ext_vector_type(4))) float f32x4;
#define MFMA16(a, b, c) __builtin_amdgcn_mfma_f32_16x16x32_bf16(a, b, c, 0, 0, 0)

struct ConvP {
  const float* w[8];
  const float* bias[8];
};

__device__ __forceinline__ ushort f2bf(float f) {
  unsigned u = __float_as_uint(f);
  u += 0x7fff + ((u >> 16) & 1);
  return (ushort)(u >> 16);
}
__device__ __forceinline__ float bf2f(short s) {
  return __uint_as_float(((unsigned)(ushort)s) << 16);
}
__device__ __forceinline__ unsigned cvtpk(float lo, float hi) {
  unsigned d;
  asm("v_cvt_pk_bf16_f32 %0, %1, %2" : "=v"(d) : "v"(lo), "v"(hi));
  return d;
}
__device__ __forceinline__ void swap3216(unsigned& a, unsigned& b) {
  asm("v_permlane32_swap_b32 %0, %1\n\t"
      "v_permlane16_swap_b32 %0, %1"
      : "+v"(a), "+v"(b));
}

// ---- prep: blocks 0..895 gather+transpose (14 tiles/b; tile 13 zeros rows
// 832-895); 896..2175 weight pack; 2176..2275 feat zero-init ----
__global__ __launch_bounds__(256) void k_prep(const int* __restrict__ x,
                                              const float* __restrict__ emb,
                                              const int* __restrict__ mask,
                                              short* __restrict__ xeb,
                                              short* __restrict__ xeT,
                                              ConvP P, short* __restrict__ wb,
                                              int* __restrict__ feat) {
  int bid = blockIdx.x;
  int t = threadIdx.x;
  if (bid >= 896) {
    if (bid >= 2176) {  // feat init
      int idx = (bid - 2176) * 256 + t;
      if (idx < BB * 2 * 4 * NFC) feat[idx] = 0;
      return;
    }
    // weight pack: wb[br][sz][nf(64)][i(5)][d(128)] zero-padded
    int idx = (bid - 896) * 256 + t;
    int d = idx & 127;
    int r = idx >> 7;
    int i = r % 5; r /= 5;
    int nf = r & 63; r >>= 6;
    int sz = r & 3;
    int br = r >> 2;
    int s = (sz < 3) ? sz + 1 : 5;
    float v = 0.f;
    if (nf < NFC && i < s && d < DD) v = P.w[br * 4 + sz][(nf * s + i) * DD + d];
    wb[idx] = (short)f2bf(v);
    return;
  }
  __shared__ float tile[64][129];
  __shared__ int toks[64];
  __shared__ float msk[64];
  int xcd = bid & 7, slot = bid >> 3;
  int b = xcd + 8 * (slot / 14);
  int mt = slot % 14;
  int m0 = mt * 64;
  if (t < 64) {
    int gm = m0 + t;
    toks[t] = (gm < LL) ? x[b * LL + gm] : 1;
    msk[t] = (gm < LL) ? (float)mask[b * LL + gm] : 0.f;
  }
  __syncthreads();
  for (int i = t; i < 64 * 128; i += 256) {
    int m = i >> 7, d = i & 127;
    int gm = m0 + m;
    float v = 0.f;
    if (gm < LL && d < DD) v = emb[(size_t)toks[m] * DD + d];
    tile[m][d] = v;
    xeb[((size_t)b * XROWS + gm) * DPAD + d] = (short)f2bf(v);
  }
  __syncthreads();
  if (m0 < MPAD) {  // xeT has only 832 m-columns
    for (int i = t; i < 64 * 128; i += 256) {
      int m = i & 63, d = i >> 6;
      float mk = msk[m];
      float v;
      if (d < DD) v = tile[m][d] * mk;
      else if (d == DD) v = mk;
      else if (d == DD + 1) v = (m0 + m < LL) ? 1.f : 0.f;
      else v = 0.f;
      xeT[((size_t)b * DPAD + d) * MPAD + m0 + m] = (short)f2bf(v);
    }
  }
}

// ---- MFMA attention (R14/R16 best-measured): 32 l-cols per wave, 128-l
// blocks, 2-phase LDS pipeline, permlane softmax, Z/S2 in-matmul ----
#define ASTR 136
#define BSTR 32
#define BOFF (32 * ASTR)
#define SBSZ (BOFF + 112 * BSTR)
__global__ __launch_bounds__(256, 3) void k_attn(const short* __restrict__ xeb,
                                                 const short* __restrict__ xeT,
                                                 const int* __restrict__ mask,
                                                 short* __restrict__ xhb) {
  __shared__ __align__(16) short SB[2][SBSZ];
  int bid = blockIdx.x;
  int xcd = bid & 7, slot = bid >> 3;  // batch -> XCD: panels stay L2-local
  int b = xcd + 8 * (slot / 7);
  int lt = slot % 7;
  int l0 = lt * 128;
  int t = threadIdx.x, w = t >> 6, lane = t & 63, g = lane >> 4, c = lane & 15;
  int lcolA = l0 + 32 * w + c;
  int lcolB = lcolA + 16;

  const short* xebB = xeb + (size_t)b * XROWS * DPAD;
  const short* xTb = xeT + (size_t)b * DPAD * MPAD;

  const short* ssrc[4];
  int sdst[4], sstep[4];
  bool sval[4];
#pragma unroll
  for (int p = 0; p < 4; ++p) {
    int q = p * 256 + w * 64 + lane;
    if (q < 512) {  // As: row r of 32-m tile, 16B piece j
      int r = q >> 4, j = q & 15;
      ssrc[p] = xebB + r * DPAD + j * 8;
      sstep[p] = 32 * DPAD;
      sdst[p] = r * ASTR + j * 8;
      sval[p] = true;
    } else {  // Bs: row r (d-dim), 16B piece j of the 32-m slice
      int u = q - 512;
      int r = u >> 2, j = u & 3;
      ssrc[p] = xTb + r * MPAD + j * 8;
      sstep[p] = 32;
      sdst[p] = BOFF + r * BSTR + j * 8;
      sval[p] = (u < 448);
    }
  }

  short8 xlfA[4], xlfB[4];
  {
    const short* ra = xebB + (size_t)lcolA * DPAD + 8 * g;
    const short* rb = xebB + (size_t)lcolB * DPAD + 8 * g;
#pragma unroll
    for (int ks = 0; ks < 4; ++ks) {
      xlfA[ks] = *reinterpret_cast<const short8*>(ra + 32 * ks);
      xlfB[ks] = *reinterpret_cast<const short8*>(rb + 32 * ks);
    }
  }

  f32x4 pvA[7], pvB[7];
#pragma unroll
  for (int dt = 0; dt < 7; ++dt) {
    pvA[dt] = (f32x4){0.f, 0.f, 0.f, 0.f};
    pvB[dt] = (f32x4){0.f, 0.f, 0.f, 0.f};
  }

  uint4 R[4];
#pragma unroll
  for (int p = 0; p < 4; ++p) {
    if (sval[p]) R[p] = *reinterpret_cast<const uint4*>(ssrc[p]);
    ssrc[p] += sstep[p];
  }

  int cur = 0;
  for (int mc = 0; mc < 26; ++mc) {
    int m0 = mc * 32;
#pragma unroll
    for (int p = 0; p < 4; ++p)
      if (sval[p]) *reinterpret_cast<short8*>(&SB[cur][sdst[p]]) =
          *reinterpret_cast<const short8*>(&R[p]);
    if (mc < 25) {
#pragma unroll
      for (int p = 0; p < 4; ++p) {
        if (sval[p]) R[p] = *reinterpret_cast<const uint4*>(ssrc[p]);
        ssrc[p] += sstep[p];
      }
    }
    asm volatile("s_waitcnt lgkmcnt(0)" ::: "memory");
    __builtin_amdgcn_s_barrier();
    __builtin_amdgcn_sched_barrier(0);

    const short* asb = SB[cur];
    const short* bsb = SB[cur] + BOFF;

    f32x4 sA0 = {0.f, 0.f, 0.f, 0.f}, sA1 = sA0, sB0 = sA0, sB1 = sA0;
    __builtin_amdgcn_s_setprio(1);
#pragma unroll
    for (int ks = 0; ks < 4; ++ks) {
      short8 af0 = *reinterpret_cast<const short8*>(asb + c * ASTR + 8 * g + 32 * ks);
      short8 af1 = *reinterpret_cast<const short8*>(asb + (c + 16) * ASTR + 8 * g + 32 * ks);
      sA0 = MFMA16(af0, xlfA[ks], sA0);
      sB0 = MFMA16(af0, xlfB[ks], sB0);
      sA1 = MFMA16(af1, xlfA[ks], sA1);
      sB1 = MFMA16(af1, xlfB[ks], sB1);
    }
    __builtin_amdgcn_s_setprio(0);

    float eA00 = __expf(sA0[0]), eA01 = __expf(sA0[1]), eA02 = __expf(sA0[2]), eA03 = __expf(sA0[3]);
    float eA10 = __expf(sA1[0]), eA11 = __expf(sA1[1]), eA12 = __expf(sA1[2]), eA13 = __expf(sA1[3]);
    float eB00 = __expf(sB0[0]), eB01 = __expf(sB0[1]), eB02 = __expf(sB0[2]), eB03 = __expf(sB0[3]);
    float eB10 = __expf(sB1[0]), eB11 = __expf(sB1[1]), eB12 = __expf(sB1[2]), eB13 = __expf(sB1[3]);
    if ((mc >> 2) == lt) {
      int md = m0 + 4 * g;
      eA00 = (md + 0 == lcolA) ? 0.f : eA00;
      eA01 = (md + 1 == lcolA) ? 0.f : eA01;
      eA02 = (md + 2 == lcolA) ? 0.f : eA02;
      eA03 = (md + 3 == lcolA) ? 0.f : eA03;
      eA10 = (md + 16 == lcolA) ? 0.f : eA10;
      eA11 = (md + 17 == lcolA) ? 0.f : eA11;
      eA12 = (md + 18 == lcolA) ? 0.f : eA12;
      eA13 = (md + 19 == lcolA) ? 0.f : eA13;
      eB00 = (md + 0 == lcolB) ? 0.f : eB00;
      eB01 = (md + 1 == lcolB) ? 0.f : eB01;
      eB02 = (md + 2 == lcolB) ? 0.f : eB02;
      eB03 = (md + 3 == lcolB) ? 0.f : eB03;
      eB10 = (md + 16 == lcolB) ? 0.f : eB10;
      eB11 = (md + 17 == lcolB) ? 0.f : eB11;
      eB12 = (md + 18 == lcolB) ? 0.f : eB12;
      eB13 = (md + 19 == lcolB) ? 0.f : eB13;
    }
    unsigned a0 = cvtpk(eA00, eA01), a1 = cvtpk(eA02, eA03);
    unsigned a2 = cvtpk(eA10, eA11), a3 = cvtpk(eA12, eA13);
    swap3216(a0, a2);
    swap3216(a1, a3);
    union { unsigned u[4]; short8 v; } paA;
    paA.u[0] = a0; paA.u[1] = a1; paA.u[2] = a2; paA.u[3] = a3;
    unsigned b0 = cvtpk(eB00, eB01), b1 = cvtpk(eB02, eB03);
    unsigned b2 = cvtpk(eB10, eB11), b3 = cvtpk(eB12, eB13);
    swap3216(b0, b2);
    swap3216(b1, b3);
    union { unsigned u[4]; short8 v; } paB;
    paB.u[0] = b0; paB.u[1] = b1; paB.u[2] = b2; paB.u[3] = b3;

    __builtin_amdgcn_s_setprio(1);
#pragma unroll
    for (int dt = 0; dt < 7; ++dt) {
      short8 bf = *reinterpret_cast<const short8*>(bsb + (c + 16 * dt) * BSTR + 8 * g);
      pvA[dt] = MFMA16(paA.v, bf, pvA[dt]);
      pvB[dt] = MFMA16(paB.v, bf, pvB[dt]);
    }
    __builtin_amdgcn_s_setprio(0);
    cur ^= 1;
  }

  // epilogue: S2 = out col 100 (lane c=4), Z = out col 101 (lane c=5)
#pragma unroll
  for (int half = 0; half < 2; ++half) {
#pragma unroll
    for (int r = 0; r < 4; ++r) {
      int lrow = l0 + 32 * w + 16 * half + 4 * g + r;
      f32x4* pv = half ? pvB : pvA;
      float S2r = __shfl(pv[6][r], 16 * g + 4);
      float Zr = __shfl(pv[6][r], 16 * g + 5) + 1.0f;  // +1: diag exp(0)
      short* xhr = xhb + ((size_t)b * XROWS + lrow) * DPAD;
      if (lrow < LL) {
        float mlr = (float)mask[b * LL + lrow];
        float inv = mlr / (mlr * S2r + Zr * 1e-13f);
        const short* xer = xebB + (size_t)lrow * DPAD;
#pragma unroll
        for (int dt = 0; dt < 7; ++dt) {
          int d = 16 * dt + c;
          xhr[d] = (d < DD) ? (short)f2bf(pv[dt][r] * inv + bf2f(xer[d])) : (short)0;
        }
        xhr[112 + c] = 0;
      } else {
#pragma unroll
        for (int dt = 0; dt < 8; ++dt) xhr[16 * dt + c] = 0;
      }
    }
  }
}

// ---- conv v5 (R16 best-measured): 2 l-tiles per block, each weight frag
// feeds 8 MFMAs (4 lsub x 2 tiles); staging sync amortized over 2x work ----
__global__ __launch_bounds__(256, 2) void k_conv(const short* __restrict__ xeb,
                                                 const short* __restrict__ xhb,
                                                 const short* __restrict__ wb,
                                                 ConvP P, int* __restrict__ feat) {
  __shared__ __align__(16) short SB[2][68 * 128];
  int bid = blockIdx.x;
  int xcd = bid & 7, slot = bid >> 3;  // batch -> XCD map (L2-local x panels)
  int b = xcd + 8 * (slot / 14);
  int rem = slot % 14;
  int br = rem >= 7;
  int q = rem % 7;
  int l0 = q * 128;
  const short* src = (br ? xhb : xeb) + (size_t)b * XROWS * DPAD;
  int t = threadIdx.x;
  int w = t >> 6, lane = t & 63, g = lane >> 4, c = lane & 15;
  int nf = w * 16 + c;
  const short* wpb = wb + (size_t)(br * 4) * 64 * 640 + (size_t)nf * 640 + 8 * g;

  float bias0 = (nf < NFC) ? P.bias[br * 4 + 0][nf] : 0.f;
  float bias1 = (nf < NFC) ? P.bias[br * 4 + 1][nf] : 0.f;
  float bias2 = (nf < NFC) ? P.bias[br * 4 + 2][nf] : 0.f;
  float bias3 = (nf < NFC) ? P.bias[br * 4 + 3][nf] : 0.f;

  // stage 2 tiles of 68x128 bf16, XOR-swizzled 16B chunks (chunk ^= row&7)
#pragma unroll
  for (int tt = 0; tt < 2; ++tt) {
    for (int i = t; i < 68 * 16; i += 256) {
      int row = i >> 4, c16 = i & 15;
      int gr = l0 + tt * 64 + row;
      if (gr > XROWS - 1) gr = XROWS - 1;  // rows >=800 are zero
      short8 v = *reinterpret_cast<const short8*>(src + (size_t)gr * DPAD + c16 * 8);
      *reinterpret_cast<short8*>(&SB[tt][row * 128 + ((c16 ^ (row & 7)) << 3)]) = v;
    }
  }
  __syncthreads();

  f32x4 acc[8][4];
#pragma unroll
  for (int ls = 0; ls < 8; ++ls)
#pragma unroll
    for (int sz = 0; sz < 4; ++sz) acc[ls][sz] = (f32x4){0.f, 0.f, 0.f, 0.f};

#pragma unroll
  for (int i2 = 0; i2 < 5; ++i2) {
#pragma unroll
    for (int ks = 0; ks < 4; ++ks) {
      short8 af[8];
#pragma unroll
      for (int tt = 0; tt < 2; ++tt)
#pragma unroll
        for (int ls = 0; ls < 4; ++ls) {
          int row = ls * 16 + c + i2;
          af[tt * 4 + ls] = *reinterpret_cast<const short8*>(
              &SB[tt][row * 128 + (((4 * ks + g) ^ (row & 7)) << 3)]);
        }
      const short* wpk = wpb + i2 * 128 + ks * 32;
      if (i2 < 1) {
        short8 w0 = *reinterpret_cast<const short8*>(wpk + (size_t)0 * 40960);
#pragma unroll
        for (int u = 0; u < 8; ++u) acc[u][0] = MFMA16(af[u], w0, acc[u][0]);
      }
      if (i2 < 2) {
        short8 w1 = *reinterpret_cast<const short8*>(wpk + (size_t)1 * 40960);
#pragma unroll
        for (int u = 0; u < 8; ++u) acc[u][1] = MFMA16(af[u], w1, acc[u][1]);
      }
      if (i2 < 3) {
        short8 w2 = *reinterpret_cast<const short8*>(wpk + (size_t)2 * 40960);
#pragma unroll
        for (int u = 0; u < 8; ++u) acc[u][2] = MFMA16(af[u], w2, acc[u][2]);
      }
      {
        short8 w3 = *reinterpret_cast<const short8*>(wpk + (size_t)3 * 40960);
#pragma unroll
        for (int u = 0; u < 8; ++u) acc[u][3] = MFMA16(af[u], w3, acc[u][3]);
      }
    }
  }

  float mx0 = 0.f, mx1 = 0.f, mx2 = 0.f, mx3 = 0.f;
#pragma unroll
  for (int u = 0; u < 8; ++u) {
    int lbase = l0 + (u >> 2) * 64 + (u & 3) * 16 + 4 * g;
#pragma unroll
    for (int r = 0; r < 4; ++r) {
      int l = lbase + r;
      float v0 = acc[u][0][r] + bias0; v0 = v0 > 0.f ? v0 : 0.f;
      float v1 = acc[u][1][r] + bias1; v1 = v1 > 0.f ? v1 : 0.f;
      float v2 = acc[u][2][r] + bias2; v2 = v2 > 0.f ? v2 : 0.f;
      float v3 = acc[u][3][r] + bias3; v3 = v3 > 0.f ? v3 : 0.f;
      if (l < LL - 0) mx0 = fmaxf(mx0, v0);
      if (l < LL - 1) mx1 = fmaxf(mx1, v1);
      if (l < LL - 2) mx2 = fmaxf(mx2, v2);
      if (l < LL - 4) mx3 = fmaxf(mx3, v3);
    }
  }

  mx0 = fmaxf(mx0, __shfl_xor(mx0, 16));
  mx0 = fmaxf(mx0, __shfl_xor(mx0, 32));
  mx1 = fmaxf(mx1, __shfl_xor(mx1, 16));
  mx1 = fmaxf(mx1, __shfl_xor(mx1, 32));
  mx2 = fmaxf(mx2, __shfl_xor(mx2, 16));
  mx2 = fmaxf(mx2, __shfl_xor(mx2, 32));
  mx3 = fmaxf(mx3, __shfl_xor(mx3, 16));
  mx3 = fmaxf(mx3, __shfl_xor(mx3, 32));
  if (g == 0 && nf < NFC) {
    int base = (b * 2 + br) * 4;
    atomicMax(&feat[(base + 0) * NFC + nf], __float_as_int(mx0));
    atomicMax(&feat[(base + 1) * NFC + nf], __float_as_int(mx1));
    atomicMax(&feat[(base + 2) * NFC + nf], __float_as_int(mx2));
    atomicMax(&feat[(base + 3) * NFC + nf], __float_as_int(mx3));
  }
}

// ---------------- FC + branch sum ----------------
__global__ __launch_bounds__(256) void k_fc(const float* __restrict__ feat,
                                            const float* __restrict__ fw1,
                                            const float* __restrict__ fb1,
                                            const float* __restrict__ fw2,
                                            const float* __restrict__ fb2,
                                            float* __restrict__ out) {
  int id = blockIdx.x * 256 + threadIdx.x;
  if (id >= BB * NFC) return;
  int b = id / NFC, k = id - b * NFC;
  float a = fb1[k] + fb2[k];
  const float* f1 = feat + (size_t)(b * 2 + 0) * (4 * NFC);
  const float* f2 = feat + (size_t)(b * 2 + 1) * (4 * NFC);
  const float* w1 = fw1 + k * (4 * NFC);
  const float* w2 = fw2 + k * (4 * NFC);
  for (int j = 0; j < 4 * NFC; ++j) a += f1[j] * w1[j] + f2[j] * w2[j];
  out[id] = a;
}

extern "C" void kernel_launch(void* const* d_in, const int* in_sizes, int n_in,
                              void* d_out, int out_size, void* d_ws, size_t ws_size,
                              hipStream_t stream) {
  const int* x = (const int*)d_in[0];
  const int* mask = (const int*)d_in[2];
  const float* emb = (const float*)d_in[3];
  ConvP P;
  for (int br = 0; br < 2; ++br)
    for (int j = 0; j < 4; ++j) {
      P.w[br * 4 + j] = (const float*)d_in[4 + br * 10 + j * 2];
      P.bias[br * 4 + j] = (const float*)d_in[4 + br * 10 + j * 2 + 1];
    }
  const float* fw1 = (const float*)d_in[12];
  const float* fb1 = (const float*)d_in[13];
  const float* fw2 = (const float*)d_in[22];
  const float* fb2 = (const float*)d_in[23];

  char* base = (char*)d_ws;
  short* xeb = (short*)base;                    // 64*896*128*2 = 14,680,064 B
  short* xeT = (short*)(base + 14680064);       // 64*128*832*2 = 13,631,488 B
  short* xhb = (short*)(base + 28311552);       // 14,680,064 B
  short* wb = (short*)(base + 42991616);        //    655,360 B
  int* feat = (int*)(base + 43646976);          //    102,400 B
  float* out = (float*)d_out;

  k_prep<<<2276, 256, 0, stream>>>(x, emb, mask, xeb, xeT, P, wb, feat);
  k_attn<<<BB * 7, 256, 0, stream>>>(xeb, xeT, mask, xhb);
  k_conv<<<BB * 2 * 7, 256, 0, stream>>>(xeb, xhb, wb, P, feat);
  k_fc<<<(BB * NFC + 255) / 256, 256, 0, stream>>>((const float*)feat, fw1, fb1,
                                                   fw2, fb2, out);
}